// Round 1
// baseline (2194.066 us; speedup 1.0000x reference)
//
#include <hip/hip_runtime.h>

#define SLEN 2048
#define BATCH 2
#define NHQ 16
#define NHKV 8
#define DIM 128

// ---------------------------------------------------------------------------
// Preprocess: for each (b, s) compute run_start / run_end of the contiguous
// run of 1s containing s (or rs=-1, re=-2 if mask[s]==0).
// bidir-allowed(q,k) <=> rs[q] >= 0 && rs[q] == rs[k]
// ---------------------------------------------------------------------------
__global__ void prep_runs(const int* __restrict__ mask,
                          int* __restrict__ rs, int* __restrict__ re) {
    __shared__ int sm[SLEN];
    const int b = blockIdx.x;
    const int* mb = mask + b * SLEN;
    for (int i = threadIdx.x; i < SLEN; i += blockDim.x) sm[i] = mb[i];
    __syncthreads();
    for (int i = threadIdx.x; i < SLEN; i += blockDim.x) {
        int s0 = -1, e0 = -2;
        if (sm[i] == 1) {
            s0 = i; while (s0 > 0 && sm[s0 - 1] == 1) --s0;
            e0 = i; while (e0 < SLEN - 1 && sm[e0 + 1] == 1) ++e0;
        }
        rs[b * SLEN + i] = s0;
        re[b * SLEN + i] = e0;
    }
}

// ---------------------------------------------------------------------------
// Flash-style attention, one wave per (b, hq, row). fp32 vector math.
// Block = 256 threads = 4 waves = 4 consecutive rows of one (b, hq).
// ---------------------------------------------------------------------------
__global__ __launch_bounds__(256) void attn_fwd(
    const float* __restrict__ Q, const float* __restrict__ K,
    const float* __restrict__ V, const int* __restrict__ rs,
    const int* __restrict__ re, const int* __restrict__ csp,
    float* __restrict__ Out)
{
    const int wid  = threadIdx.x >> 6;
    const int lane = threadIdx.x & 63;
    const int bid  = blockIdx.x;
    const int rg   = bid & (SLEN / 4 - 1);        // 512 row-groups
    const int tmp  = bid >> 9;
    const int hq   = tmp & (NHQ - 1);
    const int b    = tmp >> 4;
    const int r    = rg * 4 + wid;
    const int h    = hq >> 1;                      // GROUP = 2

    __shared__ float qs[4][DIM];

    const float scale = 0.08838834764831845f;      // 1/sqrt(128)
    const float* qp = Q + (((size_t)(b * SLEN + r) * NHQ + hq) * DIM);
    float2 qv = ((const float2*)qp)[lane];
    qs[wid][2 * lane]     = qv.x * scale;
    qs[wid][2 * lane + 1] = qv.y * scale;
    __syncthreads();

    const int cs     = csp[0];
    const int cstart = (r / cs) * cs;
    const int rsr    = rs[b * SLEN + r];
    const int rer    = re[b * SLEN + r];
    int lo = cstart; if (rsr >= 0 && rsr < lo) lo = rsr;
    int hi = r;      if (rer > hi) hi = rer;

    const size_t kvrow = (size_t)NHKV * DIM;
    const float* Kb = K + ((size_t)b * SLEN * NHKV + h) * DIM;
    const float* Vb = V + ((size_t)b * SLEN * NHKV + h) * DIM;
    const int* rsb = rs + b * SLEN;

    float m = -3.0e38f, l = 0.0f;
    float acc0 = 0.0f, acc1 = 0.0f;
    const float4* q4 = (const float4*)qs[wid];

    for (int k0 = lo; k0 <= hi; k0 += 64) {
        const int k = k0 + lane;
        bool allowed = false;
        if (k <= hi) {
            allowed = (k >= cstart && k <= r) || (rsr >= 0 && rsb[k] == rsr);
        }
        float s = -3.0e38f;
        if (allowed) {
            const float4* kp = (const float4*)(Kb + (size_t)k * kvrow);
            float d0 = 0.f, d1 = 0.f, d2 = 0.f, d3 = 0.f;
            #pragma unroll
            for (int i = 0; i < DIM / 4; i += 4) {
                float4 a, kk;
                a = q4[i];     kk = kp[i];
                d0 = fmaf(a.x, kk.x, d0); d0 = fmaf(a.y, kk.y, d0);
                d0 = fmaf(a.z, kk.z, d0); d0 = fmaf(a.w, kk.w, d0);
                a = q4[i + 1]; kk = kp[i + 1];
                d1 = fmaf(a.x, kk.x, d1); d1 = fmaf(a.y, kk.y, d1);
                d1 = fmaf(a.z, kk.z, d1); d1 = fmaf(a.w, kk.w, d1);
                a = q4[i + 2]; kk = kp[i + 2];
                d2 = fmaf(a.x, kk.x, d2); d2 = fmaf(a.y, kk.y, d2);
                d2 = fmaf(a.z, kk.z, d2); d2 = fmaf(a.w, kk.w, d2);
                a = q4[i + 3]; kk = kp[i + 3];
                d3 = fmaf(a.x, kk.x, d3); d3 = fmaf(a.y, kk.y, d3);
                d3 = fmaf(a.z, kk.z, d3); d3 = fmaf(a.w, kk.w, d3);
            }
            s = (d0 + d1) + (d2 + d3);
        }

        // wave max of s
        float smax = s;
        #pragma unroll
        for (int off = 32; off > 0; off >>= 1)
            smax = fmaxf(smax, __shfl_xor(smax, off, 64));
        const float mnew  = fmaxf(m, smax);
        const float alpha = __expf(m - mnew);
        float p = allowed ? __expf(s - mnew) : 0.0f;
        float ps = p;
        #pragma unroll
        for (int off = 32; off > 0; off >>= 1)
            ps += __shfl_xor(ps, off, 64);
        l = l * alpha + ps;
        m = mnew;
        acc0 *= alpha; acc1 *= alpha;

        // PV: broadcast p_j, coalesced float2 V loads
        const int jmax = min(hi, k0 + 63) - k0;
        for (int j = 0; j <= jmax; ++j) {
            const float pj = __shfl(p, j, 64);
            if (pj > 0.0f) {
                const float2* vp = (const float2*)(Vb + (size_t)(k0 + j) * kvrow);
                float2 vv = vp[lane];
                acc0 = fmaf(pj, vv.x, acc0);
                acc1 = fmaf(pj, vv.y, acc1);
            }
        }
    }

    const float invl = 1.0f / l;
    float2 o; o.x = acc0 * invl; o.y = acc1 * invl;
    ((float2*)(Out + (((size_t)(b * SLEN + r) * NHQ + hq) * DIM)))[lane] = o;
}

extern "C" void kernel_launch(void* const* d_in, const int* in_sizes, int n_in,
                              void* d_out, int out_size, void* d_ws, size_t ws_size,
                              hipStream_t stream) {
    const float* q  = (const float*)d_in[0];
    const float* k  = (const float*)d_in[1];
    const float* v  = (const float*)d_in[2];
    const int*   bm = (const int*)d_in[3];
    const int*   cs = (const int*)d_in[4];
    float* out = (float*)d_out;

    int* rs = (int*)d_ws;
    int* re = rs + BATCH * SLEN;

    hipLaunchKernelGGL(prep_runs, dim3(BATCH), dim3(256), 0, stream, bm, rs, re);
    hipLaunchKernelGGL(attn_fwd, dim3(BATCH * NHQ * (SLEN / 4)), dim3(256), 0, stream,
                       q, k, v, rs, re, cs, out);
}

// Round 2
// 288.017 us; speedup vs baseline: 7.6178x; 7.6178x over previous
//
#include <hip/hip_runtime.h>
#include <hip/hip_bf16.h>

#define SLEN 2048
#define BATCH 2
#define NHQ 16
#define NHKV 8
#define DIM 128

typedef __attribute__((ext_vector_type(8))) short bf16x8;
typedef __attribute__((ext_vector_type(4))) float f32x4;

static __device__ inline short f2bf(float f) {
    __hip_bfloat16 h = __float2bfloat16(f);
    return *reinterpret_cast<short*>(&h);
}

// ---------------------------------------------------------------------------
// Preprocess: run_start / run_end of the contiguous run of 1s containing s.
// rs=-1, re=-2 if mask[s]==0.  bidir-allowed(q,k) <=> rs[q]>=0 && rs[q]==rs[k]
// ---------------------------------------------------------------------------
__global__ void prep_runs(const int* __restrict__ mask,
                          int* __restrict__ rs, int* __restrict__ re) {
    __shared__ int sm[SLEN];
    const int b = blockIdx.x;
    const int* mb = mask + b * SLEN;
    for (int i = threadIdx.x; i < SLEN; i += blockDim.x) sm[i] = mb[i];
    __syncthreads();
    for (int i = threadIdx.x; i < SLEN; i += blockDim.x) {
        int s0 = -1, e0 = -2;
        if (sm[i] == 1) {
            s0 = i; while (s0 > 0 && sm[s0 - 1] == 1) --s0;
            e0 = i; while (e0 < SLEN - 1 && sm[e0 + 1] == 1) ++e0;
        }
        rs[b * SLEN + i] = s0;
        re[b * SLEN + i] = e0;
    }
}

// ---------------------------------------------------------------------------
// MFMA flash attention: one wave (block=64) per 16-row Q tile of one (b,hq).
// S-tile 16x64 via 16x16x32 bf16 MFMA; P->LDS->A-frag; PV via MFMA.
// ---------------------------------------------------------------------------
__global__ __launch_bounds__(64) void attn_fwd(
    const float* __restrict__ Q, const float* __restrict__ K,
    const float* __restrict__ V, const int* __restrict__ rs,
    const int* __restrict__ re, const int* __restrict__ csp,
    float* __restrict__ Out)
{
    const int lane = threadIdx.x;
    const int quad = lane >> 4;
    const int n    = lane & 15;

    const int bid = blockIdx.x;            // 0..4095
    const int t   = bid & (SLEN / 16 - 1); // 0..127
    const int hq  = (bid >> 7) & (NHQ - 1);
    const int b   = bid >> 11;
    const int h   = hq >> 1;               // GROUP=2
    const int r0  = t * 16;

    __shared__ float pl[16][68];           // P tile, stride 68 (2-way-free banks)

    const float scale = 0.08838834764831845f; // 1/sqrt(128)
    const int cs = csp[0];
    const int cstart = (r0 / cs) * cs;

    const int* rsb = rs + b * SLEN;
    const int* reb = re + b * SLEN;

    // tile k-range: union over rows of [min(cstart,run_start), max(r,run_end)]
    int rs_row = rsb[r0 + n];
    int re_row = reb[r0 + n];
    int lo_r = cstart;
    if (rs_row >= 0 && rs_row < lo_r) lo_r = rs_row;
    int hi_r = r0 + n;
    if (re_row > hi_r) hi_r = re_row;
    #pragma unroll
    for (int off = 8; off > 0; off >>= 1) {
        lo_r = min(lo_r, __shfl_xor(lo_r, off, 64));
        hi_r = max(hi_r, __shfl_xor(hi_r, off, 64));
    }
    const int lo_t = lo_r & ~63;
    const int hi_t = hi_r;

    // run ids for the 4 C-layout rows this lane owns (rows quad*4+g)
    int rsrv[4];
    #pragma unroll
    for (int g = 0; g < 4; ++g) rsrv[g] = rsb[r0 + quad * 4 + g];

    // Q A-frags: A[m=n][k=quad*8+j], 4 k-blocks of 32
    bf16x8 qa[4];
    {
        const float* qp = Q + (((size_t)(b * SLEN + r0 + n) * NHQ + hq) * DIM) + quad * 8;
        #pragma unroll
        for (int kb = 0; kb < 4; ++kb) {
            float4 f0 = *(const float4*)(qp + kb * 32);
            float4 f1 = *(const float4*)(qp + kb * 32 + 4);
            bf16x8 a;
            a[0] = f2bf(f0.x * scale); a[1] = f2bf(f0.y * scale);
            a[2] = f2bf(f0.z * scale); a[3] = f2bf(f0.w * scale);
            a[4] = f2bf(f1.x * scale); a[5] = f2bf(f1.y * scale);
            a[6] = f2bf(f1.z * scale); a[7] = f2bf(f1.w * scale);
            qa[kb] = a;
        }
    }

    float mrow[4], lrow[4];
    f32x4 o[8];
    #pragma unroll
    for (int g = 0; g < 4; ++g) { mrow[g] = -3.0e38f; lrow[g] = 0.0f; }
    #pragma unroll
    for (int nb = 0; nb < 8; ++nb) o[nb] = (f32x4){0.f, 0.f, 0.f, 0.f};

    const float* Kb = K + ((size_t)b * SLEN * NHKV + h) * DIM;
    const float* Vb = V + ((size_t)b * SLEN * NHKV + h) * DIM;
    const size_t kvstride = (size_t)NHKV * DIM;

    for (int k0 = lo_t; k0 <= hi_t; k0 += 64) {
        // ---- S = Q K^T (16x64) ----
        f32x4 sfr[4];
        #pragma unroll
        for (int c = 0; c < 4; ++c) {
            const int krow = min(k0 + c * 16 + n, SLEN - 1);
            const float* kp = Kb + (size_t)krow * kvstride + quad * 8;
            f32x4 acc = (f32x4){0.f, 0.f, 0.f, 0.f};
            #pragma unroll
            for (int kb = 0; kb < 4; ++kb) {
                float4 f0 = *(const float4*)(kp + kb * 32);
                float4 f1 = *(const float4*)(kp + kb * 32 + 4);
                bf16x8 bb;
                bb[0] = f2bf(f0.x); bb[1] = f2bf(f0.y);
                bb[2] = f2bf(f0.z); bb[3] = f2bf(f0.w);
                bb[4] = f2bf(f1.x); bb[5] = f2bf(f1.y);
                bb[6] = f2bf(f1.z); bb[7] = f2bf(f1.w);
                acc = __builtin_amdgcn_mfma_f32_16x16x32_bf16(qa[kb], bb, acc, 0, 0, 0);
            }
            sfr[c] = acc;
        }

        // ---- mask (skip when block fully causal-allowed) ----
        const bool fullcausal = (k0 >= cstart) && (k0 + 63 <= r0);
        if (!fullcausal) {
            #pragma unroll
            for (int c = 0; c < 4; ++c) {
                const int kcol = k0 + c * 16 + n;
                const int rsk = rsb[min(kcol, SLEN - 1)];
                const bool kin = (kcol < SLEN);
                #pragma unroll
                for (int g = 0; g < 4; ++g) {
                    const int r = r0 + quad * 4 + g;
                    const bool ok = kin && (((kcol >= cstart) && (kcol <= r)) ||
                                            (rsrv[g] >= 0 && rsk == rsrv[g]));
                    if (!ok) sfr[c][g] = -3.0e38f;
                }
            }
        }

        // ---- online softmax (rows live on 16-lane groups, 4 rows/lane) ----
        float mloc[4] = {-3.0e38f, -3.0e38f, -3.0e38f, -3.0e38f};
        #pragma unroll
        for (int c = 0; c < 4; ++c)
            #pragma unroll
            for (int g = 0; g < 4; ++g) mloc[g] = fmaxf(mloc[g], sfr[c][g]);
        #pragma unroll
        for (int off = 8; off > 0; off >>= 1)
            #pragma unroll
            for (int g = 0; g < 4; ++g)
                mloc[g] = fmaxf(mloc[g], __shfl_xor(mloc[g], off, 64));

        float alpha[4];
        #pragma unroll
        for (int g = 0; g < 4; ++g) {
            const float mnew = fmaxf(mrow[g], mloc[g]);
            alpha[g] = __expf(mrow[g] - mnew);
            mrow[g] = mnew;
        }

        float psum[4] = {0.f, 0.f, 0.f, 0.f};
        #pragma unroll
        for (int c = 0; c < 4; ++c) {
            #pragma unroll
            for (int g = 0; g < 4; ++g) {
                // masked: sfr=-3e38, mrow real -> exp(-inf)=0.
                // if mrow still -3e38 the whole row is masked so far; the
                // garbage p=1 contributions are flushed later by alpha=0.
                const float pv = __expf(sfr[c][g] - mrow[g]);
                psum[g] += pv;
                pl[quad * 4 + g][c * 16 + n] = pv;
            }
        }
        #pragma unroll
        for (int off = 8; off > 0; off >>= 1)
            #pragma unroll
            for (int g = 0; g < 4; ++g)
                psum[g] += __shfl_xor(psum[g], off, 64);
        #pragma unroll
        for (int g = 0; g < 4; ++g)
            lrow[g] = lrow[g] * alpha[g] + psum[g];
        #pragma unroll
        for (int nb = 0; nb < 8; ++nb)
            #pragma unroll
            for (int g = 0; g < 4; ++g)
                o[nb][g] *= alpha[g];

        __syncthreads();   // P writes visible to whole wave before A-frag reads

        // ---- O += P V (16x64 x 64x128) ----
        #pragma unroll
        for (int kb2 = 0; kb2 < 2; ++kb2) {
            // P A-frag: A[m=n][k=kb2*32+quad*8+j]
            const float* pp = &pl[n][kb2 * 32 + quad * 8];
            float4 f0 = *(const float4*)pp;
            float4 f1 = *(const float4*)(pp + 4);
            bf16x8 pa;
            pa[0] = f2bf(f0.x); pa[1] = f2bf(f0.y);
            pa[2] = f2bf(f0.z); pa[3] = f2bf(f0.w);
            pa[4] = f2bf(f1.x); pa[5] = f2bf(f1.y);
            pa[6] = f2bf(f1.z); pa[7] = f2bf(f1.w);

            const float* vrow[8];
            #pragma unroll
            for (int j = 0; j < 8; ++j) {
                const int k = min(k0 + kb2 * 32 + quad * 8 + j, SLEN - 1);
                vrow[j] = Vb + (size_t)k * kvstride + n;
            }
            #pragma unroll
            for (int nb = 0; nb < 8; ++nb) {
                bf16x8 vb;
                #pragma unroll
                for (int j = 0; j < 8; ++j)
                    vb[j] = f2bf(vrow[j][nb * 16]);
                o[nb] = __builtin_amdgcn_mfma_f32_16x16x32_bf16(pa, vb, o[nb], 0, 0, 0);
            }
        }
        __syncthreads();   // P reads done before next iteration overwrites
    }

    // ---- epilogue ----
    #pragma unroll
    for (int g = 0; g < 4; ++g) {
        const float inv = 1.0f / lrow[g];
        const int r = r0 + quad * 4 + g;
        float* op = Out + ((size_t)(b * SLEN + r) * NHQ + hq) * DIM + n;
        #pragma unroll
        for (int nb = 0; nb < 8; ++nb)
            op[nb * 16] = o[nb][g] * inv;
    }
}

extern "C" void kernel_launch(void* const* d_in, const int* in_sizes, int n_in,
                              void* d_out, int out_size, void* d_ws, size_t ws_size,
                              hipStream_t stream) {
    const float* q  = (const float*)d_in[0];
    const float* k  = (const float*)d_in[1];
    const float* v  = (const float*)d_in[2];
    const int*   bm = (const int*)d_in[3];
    const int*   cs = (const int*)d_in[4];
    float* out = (float*)d_out;

    int* rs = (int*)d_ws;
    int* re = rs + BATCH * SLEN;

    hipLaunchKernelGGL(prep_runs, dim3(BATCH), dim3(256), 0, stream, bm, rs, re);
    hipLaunchKernelGGL(attn_fwd, dim3(BATCH * NHQ * (SLEN / 16)), dim3(64), 0, stream,
                       q, k, v, rs, re, cs, out);
}

// Round 3
// 257.752 us; speedup vs baseline: 8.5123x; 1.1174x over previous
//
#include <hip/hip_runtime.h>
#include <hip/hip_bf16.h>

#define SLEN 2048
#define BATCH 2
#define NHQ 16
#define NHKV 8
#define DIM 128

#define PSTRIDE 76   // fp32 words per P row (16B-aligned rows, full bank spread)
#define VSTRIDE 36   // u32 words per V_t row = 72 bf16 (16B-aligned rows)

typedef __attribute__((ext_vector_type(8))) short bf16x8;
typedef __attribute__((ext_vector_type(4))) float f32x4;

static __device__ inline short f2bf(float f) {
    __hip_bfloat16 h = __float2bfloat16(f);
    return *reinterpret_cast<short*>(&h);
}
static __device__ inline unsigned pack_bf2(float lo, float hi) {
    unsigned a = (unsigned)(unsigned short)f2bf(lo);
    unsigned b = (unsigned)(unsigned short)f2bf(hi);
    return a | (b << 16);
}

// ---------------------------------------------------------------------------
// Preprocess: run_start / run_end of the contiguous run of 1s containing s.
// rs=-1, re=-2 if mask[s]==0.  bidir-allowed(q,k) <=> rs[q]>=0 && rs[q]==rs[k]
// ---------------------------------------------------------------------------
__global__ void prep_runs(const int* __restrict__ mask,
                          int* __restrict__ rs, int* __restrict__ re) {
    __shared__ int sm[SLEN];
    const int b = blockIdx.x;
    const int* mb = mask + b * SLEN;
    for (int i = threadIdx.x; i < SLEN; i += blockDim.x) sm[i] = mb[i];
    __syncthreads();
    for (int i = threadIdx.x; i < SLEN; i += blockDim.x) {
        int s0 = -1, e0 = -2;
        if (sm[i] == 1) {
            s0 = i; while (s0 > 0 && sm[s0 - 1] == 1) --s0;
            e0 = i; while (e0 < SLEN - 1 && sm[e0 + 1] == 1) ++e0;
        }
        rs[b * SLEN + i] = s0;
        re[b * SLEN + i] = e0;
    }
}

// ---------------------------------------------------------------------------
// MFMA flash attention.
// Block = 256 thr = 4 waves, handles (b, kv-head h, 32-row group):
//   wave w -> head hq = 2h + (w&1), rows r0 = rg*32 + (w>>1)*16.
// All 4 waves share one k-range (mask is head-independent) and one LDS-staged
// V tile (transposed bf16, ds_read_b128 B-frags). K is gathered per-lane
// (16B contiguous) as in round 2; 4 blocks/CU hide the latency.
// ---------------------------------------------------------------------------
__global__ __launch_bounds__(256, 4) void attn_fwd(
    const float* __restrict__ Q, const float* __restrict__ K,
    const float* __restrict__ V, const int* __restrict__ rs,
    const int* __restrict__ re, const int* __restrict__ csp,
    float* __restrict__ Out)
{
    const int tid  = threadIdx.x;
    const int wid  = tid >> 6;
    const int lane = tid & 63;
    const int quad = lane >> 4;
    const int n    = lane & 15;

    const int bid   = blockIdx.x;            // 0..1023
    const int rg    = bid & (SLEN / 32 - 1); // 0..63
    const int h     = (bid >> 6) & (NHKV - 1);
    const int b     = bid >> 9;
    const int hq    = 2 * h + (wid & 1);
    const int rbase = rg * 32;
    const int r0    = rbase + (wid >> 1) * 16;

    __shared__ unsigned vt[128 * VSTRIDE];     // V^T tile, bf16-pair packed
    __shared__ float    pl[4][16 * PSTRIDE];   // per-wave P tiles

    const float scale = 0.08838834764831845f;  // 1/sqrt(128)
    const int cs      = csp[0];
    const int cstart  = (rbase / cs) * cs;     // same chunk for all 32 rows

    const int* rsb = rs + b * SLEN;
    const int* reb = re + b * SLEN;

    // block k-range: union over the 32 rows (identical in every wave)
    {
    }
    int row_l = rbase + (lane & 31);
    int rsv = rsb[row_l], rev = reb[row_l];
    int lo_r = cstart; if (rsv >= 0 && rsv < lo_r) lo_r = rsv;
    int hi_r = row_l;  if (rev > hi_r) hi_r = rev;
    #pragma unroll
    for (int off = 32; off > 0; off >>= 1) {
        lo_r = min(lo_r, __shfl_xor(lo_r, off, 64));
        hi_r = max(hi_r, __shfl_xor(hi_r, off, 64));
    }
    const int lo_t = lo_r & ~63;
    const int hi_t = hi_r;

    // run ids for the 4 C-layout rows this lane owns (rows r0 + quad*4+g)
    int rsrv[4];
    #pragma unroll
    for (int g = 0; g < 4; ++g) rsrv[g] = rsb[r0 + quad * 4 + g];

    // Q A-frags: A[m=n][k=quad*8+j], 4 k-blocks of 32
    bf16x8 qa[4];
    {
        const float* qp = Q + (((size_t)(b * SLEN + r0 + n) * NHQ + hq) * DIM) + quad * 8;
        #pragma unroll
        for (int kb = 0; kb < 4; ++kb) {
            float4 f0 = *(const float4*)(qp + kb * 32);
            float4 f1 = *(const float4*)(qp + kb * 32 + 4);
            bf16x8 a;
            a[0] = f2bf(f0.x * scale); a[1] = f2bf(f0.y * scale);
            a[2] = f2bf(f0.z * scale); a[3] = f2bf(f0.w * scale);
            a[4] = f2bf(f1.x * scale); a[5] = f2bf(f1.y * scale);
            a[6] = f2bf(f1.z * scale); a[7] = f2bf(f1.w * scale);
            qa[kb] = a;
        }
    }

    float mrow[4], lrow[4];
    f32x4 o[8];
    #pragma unroll
    for (int g = 0; g < 4; ++g) { mrow[g] = -3.0e38f; lrow[g] = 0.0f; }
    #pragma unroll
    for (int nb = 0; nb < 8; ++nb) o[nb] = (f32x4){0.f, 0.f, 0.f, 0.f};

    const float* Kb = K + ((size_t)b * SLEN * NHKV + h) * DIM;
    const float* Vb = V + ((size_t)b * SLEN * NHKV + h) * DIM;
    const size_t kvstride = (size_t)NHKV * DIM;

    const int vc = tid & 127;   // V staging: column
    const int vk = tid >> 7;    // V staging: pair-phase

    for (int k0 = lo_t; k0 <= hi_t; k0 += 64) {
        __syncthreads();   // prev iter's vt reads done before overwrite

        // ---- stage V tile (64 keys x 128 cols), transposed, bf16-packed ----
        #pragma unroll
        for (int i = 0; i < 16; ++i) {
            const int j = i * 2 + vk;               // key-pair 0..31
            int r1 = k0 + 2 * j, r2 = r1 + 1;
            r1 = min(r1, SLEN - 1); r2 = min(r2, SLEN - 1);
            const float a = Vb[(size_t)r1 * kvstride + vc];
            const float d = Vb[(size_t)r2 * kvstride + vc];
            vt[vc * VSTRIDE + j] = pack_bf2(a, d);
        }
        __syncthreads();   // vt visible

        // ---- S = Q K^T (16x64), K gathered per-lane (16B contiguous) ----
        f32x4 sfr[4];
        #pragma unroll
        for (int c = 0; c < 4; ++c) {
            const int krow = min(k0 + c * 16 + n, SLEN - 1);
            const float* kp = Kb + (size_t)krow * kvstride + quad * 8;
            f32x4 acc = (f32x4){0.f, 0.f, 0.f, 0.f};
            #pragma unroll
            for (int kb = 0; kb < 4; ++kb) {
                float4 f0 = *(const float4*)(kp + kb * 32);
                float4 f1 = *(const float4*)(kp + kb * 32 + 4);
                bf16x8 bb;
                bb[0] = f2bf(f0.x); bb[1] = f2bf(f0.y);
                bb[2] = f2bf(f0.z); bb[3] = f2bf(f0.w);
                bb[4] = f2bf(f1.x); bb[5] = f2bf(f1.y);
                bb[6] = f2bf(f1.z); bb[7] = f2bf(f1.w);
                acc = __builtin_amdgcn_mfma_f32_16x16x32_bf16(qa[kb], bb, acc, 0, 0, 0);
            }
            sfr[c] = acc;
        }

        // ---- mask (skip when block fully causal-allowed) ----
        const bool fullcausal = (k0 >= cstart) && (k0 + 63 <= r0);
        if (!fullcausal) {
            #pragma unroll
            for (int c = 0; c < 4; ++c) {
                const int kcol = k0 + c * 16 + n;
                const int rsk  = rsb[min(kcol, SLEN - 1)];
                const bool kin = (kcol < SLEN);
                #pragma unroll
                for (int g = 0; g < 4; ++g) {
                    const int r = r0 + quad * 4 + g;
                    const bool ok = kin && (((kcol >= cstart) && (kcol <= r)) ||
                                            (rsrv[g] >= 0 && rsk == rsrv[g]));
                    if (!ok) sfr[c][g] = -3.0e38f;
                }
            }
        }

        // ---- online softmax (rows on 16-lane groups, 4 rows/lane) ----
        float mloc[4] = {-3.0e38f, -3.0e38f, -3.0e38f, -3.0e38f};
        #pragma unroll
        for (int c = 0; c < 4; ++c)
            #pragma unroll
            for (int g = 0; g < 4; ++g) mloc[g] = fmaxf(mloc[g], sfr[c][g]);
        #pragma unroll
        for (int off = 8; off > 0; off >>= 1)
            #pragma unroll
            for (int g = 0; g < 4; ++g)
                mloc[g] = fmaxf(mloc[g], __shfl_xor(mloc[g], off, 64));

        float alpha[4];
        #pragma unroll
        for (int g = 0; g < 4; ++g) {
            const float mnew = fmaxf(mrow[g], mloc[g]);
            alpha[g] = __expf(mrow[g] - mnew);
            mrow[g] = mnew;
        }

        float psum[4] = {0.f, 0.f, 0.f, 0.f};
        #pragma unroll
        for (int c = 0; c < 4; ++c) {
            #pragma unroll
            for (int g = 0; g < 4; ++g) {
                // masked lanes: exp(-3e38 - m) == 0 once m is real; if the
                // whole row is still masked (m==-3e38) the garbage p==1 is
                // flushed later by alpha==0 when a real value arrives (the
                // causal diagonal guarantees one).
                const float pv = __expf(sfr[c][g] - mrow[g]);
                psum[g] += pv;
                pl[wid][(quad * 4 + g) * PSTRIDE + c * 16 + n] = pv;
            }
        }
        #pragma unroll
        for (int off = 8; off > 0; off >>= 1)
            #pragma unroll
            for (int g = 0; g < 4; ++g)
                psum[g] += __shfl_xor(psum[g], off, 64);
        #pragma unroll
        for (int g = 0; g < 4; ++g)
            lrow[g] = lrow[g] * alpha[g] + psum[g];
        #pragma unroll
        for (int nb = 0; nb < 8; ++nb)
            #pragma unroll
            for (int g = 0; g < 4; ++g)
                o[nb][g] *= alpha[g];

        __syncthreads();   // P writes visible (waves run identical trip counts)

        // ---- O += P V : A-frag from pl, B-frag = ds_read_b128 from vt ----
        #pragma unroll
        for (int kb2 = 0; kb2 < 2; ++kb2) {
            const float* pp = &pl[wid][n * PSTRIDE + kb2 * 32 + quad * 8];
            float4 f0 = *(const float4*)pp;
            float4 f1 = *(const float4*)(pp + 4);
            bf16x8 pa;
            pa[0] = f2bf(f0.x); pa[1] = f2bf(f0.y);
            pa[2] = f2bf(f0.z); pa[3] = f2bf(f0.w);
            pa[4] = f2bf(f1.x); pa[5] = f2bf(f1.y);
            pa[6] = f2bf(f1.z); pa[7] = f2bf(f1.w);

            #pragma unroll
            for (int nb = 0; nb < 8; ++nb) {
                const unsigned* vp = &vt[(nb * 16 + n) * VSTRIDE + kb2 * 16 + quad * 4];
                bf16x8 vb = *(const bf16x8*)vp;   // 16B aligned
                o[nb] = __builtin_amdgcn_mfma_f32_16x16x32_bf16(pa, vb, o[nb], 0, 0, 0);
            }
        }
    }

    // ---- epilogue ----
    #pragma unroll
    for (int g = 0; g < 4; ++g) {
        const float inv = 1.0f / lrow[g];
        const int r = r0 + quad * 4 + g;
        float* op = Out + ((size_t)(b * SLEN + r) * NHQ + hq) * DIM + n;
        #pragma unroll
        for (int nb = 0; nb < 8; ++nb)
            op[nb * 16] = o[nb][g] * inv;
    }
}

extern "C" void kernel_launch(void* const* d_in, const int* in_sizes, int n_in,
                              void* d_out, int out_size, void* d_ws, size_t ws_size,
                              hipStream_t stream) {
    const float* q  = (const float*)d_in[0];
    const float* k  = (const float*)d_in[1];
    const float* v  = (const float*)d_in[2];
    const int*   bm = (const int*)d_in[3];
    const int*   cs = (const int*)d_in[4];
    float* out = (float*)d_out;

    int* rs = (int*)d_ws;
    int* re = rs + BATCH * SLEN;

    hipLaunchKernelGGL(prep_runs, dim3(BATCH), dim3(256), 0, stream, bm, rs, re);
    hipLaunchKernelGGL(attn_fwd, dim3(BATCH * NHKV * (SLEN / 32)), dim3(256), 0, stream,
                       q, k, v, rs, re, cs, out);
}